// Round 1
// baseline (6672.020 us; speedup 1.0000x reference)
//
#include <hip/hip_runtime.h>

#define N_GRAPHS 64

// ---------------------------------------------------------------------------
// deg[c] += 1 for each edge target c (self-loop +1 added later in k_dinv)
__global__ void k_deg(const int* __restrict__ col, int* __restrict__ deg, int E) {
    int e = blockIdx.x * blockDim.x + threadIdx.x;
    if (e < E) atomicAdd(&deg[col[e]], 1);
}

// dinv[i] = rsqrt(deg[i] + 1)   (+1 = self loop; always > 0)
__global__ void k_dinv(const int* __restrict__ deg, float* __restrict__ dinv, int n) {
    int i = blockIdx.x * blockDim.x + threadIdx.x;
    if (i < n) dinv[i] = rsqrtf((float)(deg[i] + 1));
}

// aggx[i][k] = x[i][k] * dinv[i]^2   (self-loop contribution seeds the buffer)
__global__ void k_init1(const float* __restrict__ x, const float* __restrict__ dinv,
                        float* __restrict__ aggx, int n) {
    int i = blockIdx.x * blockDim.x + threadIdx.x;
    if (i >= n) return;
    float d = dinv[i];
    float s = d * d;
#pragma unroll
    for (int k = 0; k < 7; k++) aggx[i * 7 + k] = x[i * 7 + k] * s;
}

// aggx[c] += x[r] * dinv[r]*dinv[c]   (7 features per edge)
__global__ void k_edge1(const int* __restrict__ row, const int* __restrict__ colv,
                        const float* __restrict__ x, const float* __restrict__ dinv,
                        float* __restrict__ aggx, int E) {
    int e = blockIdx.x * blockDim.x + threadIdx.x;
    if (e >= E) return;
    int r = row[e], c = colv[e];
    float nrm = dinv[r] * dinv[c];
    const float* xr = x + (size_t)r * 7;
    float* out = aggx + (size_t)c * 7;
#pragma unroll
    for (int k = 0; k < 7; k++) atomicAdd(&out[k], xr[k] * nrm);
}

// Per node: h1 = relu(aggx @ W1 + b1)  [64];  h1p = h1 @ W2  [32]
// Also seed layer-2 aggregation with the self loop: agg2[i] = h1p[i]*dinv[i]^2
__global__ __launch_bounds__(256) void k_mlp1(
        const float* __restrict__ aggx, const float* __restrict__ dinv,
        const float* __restrict__ W1, const float* __restrict__ b1,
        const float* __restrict__ W2,
        float* __restrict__ h1p, float* __restrict__ agg2, int n) {
    __shared__ float sW1[7 * 64];
    __shared__ float sb1[64];
    __shared__ float sW2[64 * 32];
    for (int t = threadIdx.x; t < 7 * 64; t += blockDim.x) sW1[t] = W1[t];
    for (int t = threadIdx.x; t < 64; t += blockDim.x) sb1[t] = b1[t];
    for (int t = threadIdx.x; t < 64 * 32; t += blockDim.x) sW2[t] = W2[t];
    __syncthreads();

    int i = blockIdx.x * blockDim.x + threadIdx.x;
    if (i >= n) return;

    float a[7];
#pragma unroll
    for (int k = 0; k < 7; k++) a[k] = aggx[i * 7 + k];

    float acc[32];
#pragma unroll
    for (int m = 0; m < 32; m++) acc[m] = 0.f;

    for (int j = 0; j < 64; j++) {
        float v = sb1[j];
#pragma unroll
        for (int k = 0; k < 7; k++) v += a[k] * sW1[k * 64 + j];
        v = fmaxf(v, 0.f);  // relu(conv1)
#pragma unroll
        for (int m = 0; m < 32; m++) acc[m] += v * sW2[j * 32 + m];
    }

    float d = dinv[i];
    float s = d * d;
#pragma unroll
    for (int m = 0; m < 32; m++) {
        h1p[(size_t)i * 32 + m] = acc[m];
        agg2[(size_t)i * 32 + m] = acc[m] * s;
    }
}

// agg2[c] += h1p[r] * dinv[r]*dinv[c]   (32 features per edge)
__global__ void k_edge2(const int* __restrict__ row, const int* __restrict__ colv,
                        const float* __restrict__ h1p, const float* __restrict__ dinv,
                        float* __restrict__ agg2, int E) {
    int e = blockIdx.x * blockDim.x + threadIdx.x;
    if (e >= E) return;
    int r = row[e], c = colv[e];
    float nrm = dinv[r] * dinv[c];
    const float4* hp = (const float4*)(h1p + (size_t)r * 32);
    float* out = agg2 + (size_t)c * 32;
#pragma unroll
    for (int q = 0; q < 8; q++) {
        float4 v = hp[q];
        atomicAdd(&out[q * 4 + 0], v.x * nrm);
        atomicAdd(&out[q * 4 + 1], v.y * nrm);
        atomicAdd(&out[q * 4 + 2], v.z * nrm);
        atomicAdd(&out[q * 4 + 3], v.w * nrm);
    }
}

// Per node: h2 = relu(agg2 + b2); wave-reduce per graph (batch is sorted) and
// atomically add the per-wave partial sums + counts to psum/pcnt.
__global__ __launch_bounds__(256) void k_pool(
        const float* __restrict__ agg2, const float* __restrict__ b2,
        const int* __restrict__ batch,
        float* __restrict__ psum, int* __restrict__ pcnt, int n) {
    int i = blockIdx.x * blockDim.x + threadIdx.x;
    bool valid = (i < n);
    int isafe = valid ? i : (n - 1);
    int g = batch[isafe];

    float v[32];
#pragma unroll
    for (int m = 0; m < 32; m++) {
        float t = agg2[(size_t)isafe * 32 + m] + b2[m];
        v[m] = valid ? fmaxf(t, 0.f) : 0.f;
    }

    int g0 = __shfl(g, 0);
    if (__all(g == g0)) {
        // graph-uniform wave (the common case: ~1562 nodes/graph, sorted)
#pragma unroll
        for (int step = 1; step < 64; step <<= 1) {
#pragma unroll
            for (int m = 0; m < 32; m++) v[m] += __shfl_xor(v[m], step);
        }
        unsigned long long mask = __ballot(valid);
        int lane = threadIdx.x & 63;
        if (lane == 0) {
#pragma unroll
            for (int m = 0; m < 32; m++) atomicAdd(&psum[g0 * 32 + m], v[m]);
            atomicAdd(&pcnt[g0], (int)__popcll(mask));
        }
    } else {
        // graph boundary inside the wave (rare)
        if (valid) {
#pragma unroll
            for (int m = 0; m < 32; m++) atomicAdd(&psum[g * 32 + m], v[m]);
            atomicAdd(&pcnt[g], 1);
        }
    }
}

// out[g][o] = (sum_m psum[g][m] * Wl[m][o]) / max(cnt,1) + bl[o]
__global__ void k_out(const float* __restrict__ psum, const int* __restrict__ pcnt,
                      const float* __restrict__ Wl, const float* __restrict__ bl,
                      float* __restrict__ out) {
    int t = blockIdx.x * blockDim.x + threadIdx.x;
    if (t >= N_GRAPHS * 5) return;
    int g = t / 5, o = t % 5;
    float c = (float)max(pcnt[g], 1);
    float acc = 0.f;
#pragma unroll
    for (int m = 0; m < 32; m++) acc += psum[g * 32 + m] * Wl[m * 5 + o];
    out[t] = acc / c + bl[o];
}

extern "C" void kernel_launch(void* const* d_in, const int* in_sizes, int n_in,
                              void* d_out, int out_size, void* d_ws, size_t ws_size,
                              hipStream_t stream) {
    const float* x     = (const float*)d_in[0];
    const int*   ei    = (const int*)d_in[1];
    const int*   batch = (const int*)d_in[2];
    const float* W1    = (const float*)d_in[3];
    const float* b1    = (const float*)d_in[4];
    const float* W2    = (const float*)d_in[5];
    const float* b2    = (const float*)d_in[6];
    const float* Wl    = (const float*)d_in[7];
    const float* bl    = (const float*)d_in[8];
    float* out = (float*)d_out;

    const int n = in_sizes[0] / 7;        // 100000
    const int E = in_sizes[1] / 2;        // 3200000
    const int* row = ei;                  // edge_index[0]
    const int* col = ei + E;              // edge_index[1]

    // workspace carve-up (256B aligned)
    char* p = (char*)d_ws;
    auto alloc = [&](size_t bytes) -> char* {
        char* r = p;
        p += (bytes + 255) & ~(size_t)255;
        return r;
    };
    int*   deg  = (int*)  alloc((size_t)n * 4);
    float* dinv = (float*)alloc((size_t)n * 4);
    float* aggx = (float*)alloc((size_t)n * 7 * 4);
    float* h1p  = (float*)alloc((size_t)n * 32 * 4);
    float* agg2 = (float*)alloc((size_t)n * 32 * 4);
    float* psum = (float*)alloc((size_t)N_GRAPHS * 32 * 4);
    int*   pcnt = (int*)  alloc((size_t)N_GRAPHS * 4);

    hipMemsetAsync(deg, 0, (size_t)n * 4, stream);
    hipMemsetAsync(psum, 0, (size_t)N_GRAPHS * 32 * 4 + 256 /*covers pcnt pad*/, stream);
    hipMemsetAsync(pcnt, 0, (size_t)N_GRAPHS * 4, stream);

    const int BT = 256;
    int nb_n = (n + BT - 1) / BT;
    int nb_e = (E + BT - 1) / BT;

    k_deg  <<<nb_e, BT, 0, stream>>>(col, deg, E);
    k_dinv <<<nb_n, BT, 0, stream>>>(deg, dinv, n);
    k_init1<<<nb_n, BT, 0, stream>>>(x, dinv, aggx, n);
    k_edge1<<<nb_e, BT, 0, stream>>>(row, col, x, dinv, aggx, E);
    k_mlp1 <<<nb_n, BT, 0, stream>>>(aggx, dinv, W1, b1, W2, h1p, agg2, n);
    k_edge2<<<nb_e, BT, 0, stream>>>(row, col, h1p, dinv, agg2, E);
    k_pool <<<nb_n, BT, 0, stream>>>(agg2, b2, batch, psum, pcnt, n);
    k_out  <<<1, 320, 0, stream>>>(psum, pcnt, Wl, bl, out);
}

// Round 2
// 668.889 us; speedup vs baseline: 9.9748x; 9.9748x over previous
//
#include <hip/hip_runtime.h>

#define N_GRAPHS 64

// ---------------------------------------------------------------------------
// CSR build stage 1: in-degree count (self-loop handled analytically later)
__global__ void k_deg(const int* __restrict__ col, int* __restrict__ deg, int E) {
    int e = blockIdx.x * blockDim.x + threadIdx.x;
    if (e < E) atomicAdd(&deg[col[e]], 1);
}

// dinv[i] = rsqrt(deg[i] + 1)   (+1 = self loop; always > 0)
__global__ void k_dinv(const int* __restrict__ deg, float* __restrict__ dinv, int n) {
    int i = blockIdx.x * blockDim.x + threadIdx.x;
    if (i < n) dinv[i] = rsqrtf((float)(deg[i] + 1));
}

// ---------------------------------------------------------------------------
// Exclusive scan of deg -> off.  1024 elements per 256-thread block.
__global__ __launch_bounds__(256) void k_scan_partial(
        const int* __restrict__ deg, int* __restrict__ off,
        int* __restrict__ bsum, int n) {
    __shared__ int lds[256];
    int t = threadIdx.x;
    int base = blockIdx.x * 1024 + t * 4;
    int v[4], s = 0;
#pragma unroll
    for (int q = 0; q < 4; q++) {
        v[q] = (base + q < n) ? deg[base + q] : 0;
        s += v[q];
    }
    lds[t] = s;
    __syncthreads();
    // Hillis-Steele inclusive scan over 256 thread-sums
    for (int d = 1; d < 256; d <<= 1) {
        int tmp = (t >= d) ? lds[t - d] : 0;
        __syncthreads();
        lds[t] += tmp;
        __syncthreads();
    }
    int excl = lds[t] - s;   // exclusive offset of this thread within block
    int run = excl;
#pragma unroll
    for (int q = 0; q < 4; q++) {
        if (base + q < n) off[base + q] = run;
        run += v[q];
    }
    if (t == 255) bsum[blockIdx.x] = lds[255];
}

// single block scans the (<=128) block sums -> exclusive block offsets
__global__ void k_scan_blocks(const int* __restrict__ bsum,
                              int* __restrict__ bexcl, int nb) {
    __shared__ int lds[128];
    int t = threadIdx.x;
    int v = (t < nb) ? bsum[t] : 0;
    lds[t] = v;
    __syncthreads();
    for (int d = 1; d < 128; d <<= 1) {
        int tmp = (t >= d) ? lds[t - d] : 0;
        __syncthreads();
        lds[t] += tmp;
        __syncthreads();
    }
    if (t < nb) bexcl[t] = lds[t] - v;
}

__global__ void k_scan_add(int* __restrict__ off, const int* __restrict__ bexcl,
                           int n, int E) {
    int i = blockIdx.x * blockDim.x + threadIdx.x;
    if (i < n) off[i] += bexcl[i >> 10];
    if (i == 0) off[n] = E;
}

// CSR build stage 2: scatter edges into per-target buckets.
// wnorm = dinv[r]*dinv[c] precomputed so agg kernels read contiguous streams.
__global__ void k_scatter(const int* __restrict__ row, const int* __restrict__ colv,
                          const int* __restrict__ off, int* __restrict__ cursor,
                          const float* __restrict__ dinv,
                          int* __restrict__ srow, float* __restrict__ wnorm, int E) {
    int e = blockIdx.x * blockDim.x + threadIdx.x;
    if (e >= E) return;
    int r = row[e], c = colv[e];
    int slot = atomicAdd(&cursor[c], 1);
    int p = off[c] + slot;
    srow[p] = r;
    wnorm[p] = dinv[r] * dinv[c];
}

// ---------------------------------------------------------------------------
// Layer-1 aggregation (gather): one wave per node, 7 features.
// lane = es*8 + f :  f in [0,8) (7 valid), es in [0,8) -> 8 edges/iter.
__global__ __launch_bounds__(256) void k_agg1(
        const float* __restrict__ x, const float* __restrict__ dinv,
        const int* __restrict__ off, const int* __restrict__ srow,
        const float* __restrict__ wnorm, float* __restrict__ aggx, int n) {
    int wid = (blockIdx.x * blockDim.x + threadIdx.x) >> 6;
    if (wid >= n) return;
    int lane = threadIdx.x & 63;
    int f = lane & 7, es = lane >> 3;
    int c = wid;
    int o0 = off[c], o1 = off[c + 1];
    float acc = 0.f;
    if (es == 0 && f < 7) {
        float dc = dinv[c];
        acc = x[(size_t)c * 7 + f] * dc * dc;      // self loop
    }
    for (int j = o0 + es; j < o1; j += 8) {
        int r = srow[j];
        float w = wnorm[j];
        if (f < 7) acc += x[(size_t)r * 7 + f] * w;
    }
    acc += __shfl_xor(acc, 8);
    acc += __shfl_xor(acc, 16);
    acc += __shfl_xor(acc, 32);
    if (es == 0 && f < 7) aggx[(size_t)c * 7 + f] = acc;
}

// Per node: h1 = relu(aggx @ W1 + b1)  [64];  h1p = h1 @ W2  [32]
__global__ __launch_bounds__(256) void k_mlp1(
        const float* __restrict__ aggx,
        const float* __restrict__ W1, const float* __restrict__ b1,
        const float* __restrict__ W2,
        float* __restrict__ h1p, int n) {
    __shared__ float sW1[7 * 64];
    __shared__ float sb1[64];
    __shared__ float sW2[64 * 32];
    for (int t = threadIdx.x; t < 7 * 64; t += blockDim.x) sW1[t] = W1[t];
    for (int t = threadIdx.x; t < 64; t += blockDim.x) sb1[t] = b1[t];
    for (int t = threadIdx.x; t < 64 * 32; t += blockDim.x) sW2[t] = W2[t];
    __syncthreads();

    int i = blockIdx.x * blockDim.x + threadIdx.x;
    if (i >= n) return;

    float a[7];
#pragma unroll
    for (int k = 0; k < 7; k++) a[k] = aggx[(size_t)i * 7 + k];

    float acc[32];
#pragma unroll
    for (int m = 0; m < 32; m++) acc[m] = 0.f;

    for (int j = 0; j < 64; j++) {
        float v = sb1[j];
#pragma unroll
        for (int k = 0; k < 7; k++) v += a[k] * sW1[k * 64 + j];
        v = fmaxf(v, 0.f);  // relu(conv1)
#pragma unroll
        for (int m = 0; m < 32; m++) acc[m] += v * sW2[j * 32 + m];
    }
#pragma unroll
    for (int m = 0; m < 32; m++) h1p[(size_t)i * 32 + m] = acc[m];
}

// Layer-2 aggregation (gather): one wave per node, 32 features.
// lane = es*32 + f : f in [0,32), es in [0,2) -> 2 edges/iter.
__global__ __launch_bounds__(256) void k_agg2(
        const float* __restrict__ h1p, const float* __restrict__ dinv,
        const int* __restrict__ off, const int* __restrict__ srow,
        const float* __restrict__ wnorm, float* __restrict__ agg2, int n) {
    int wid = (blockIdx.x * blockDim.x + threadIdx.x) >> 6;
    if (wid >= n) return;
    int lane = threadIdx.x & 63;
    int f = lane & 31, es = lane >> 5;
    int c = wid;
    int o0 = off[c], o1 = off[c + 1];
    float acc = 0.f;
    if (es == 0) {
        float dc = dinv[c];
        acc = h1p[(size_t)c * 32 + f] * dc * dc;   // self loop
    }
    for (int j = o0 + es; j < o1; j += 2) {
        acc += h1p[(size_t)srow[j] * 32 + f] * wnorm[j];
    }
    acc += __shfl_xor(acc, 32);
    if (es == 0) agg2[(size_t)c * 32 + f] = acc;
}

// Per node: h2 = relu(agg2 + b2); wave-reduce per graph (batch sorted), one
// atomic set per wave into psum/pcnt.
__global__ __launch_bounds__(256) void k_pool(
        const float* __restrict__ agg2, const float* __restrict__ b2,
        const int* __restrict__ batch,
        float* __restrict__ psum, int* __restrict__ pcnt, int n) {
    int i = blockIdx.x * blockDim.x + threadIdx.x;
    bool valid = (i < n);
    int isafe = valid ? i : (n - 1);
    int g = batch[isafe];

    float v[32];
#pragma unroll
    for (int m = 0; m < 32; m++) {
        float t = agg2[(size_t)isafe * 32 + m] + b2[m];
        v[m] = valid ? fmaxf(t, 0.f) : 0.f;
    }

    int g0 = __shfl(g, 0);
    if (__all(g == g0)) {
#pragma unroll
        for (int step = 1; step < 64; step <<= 1) {
#pragma unroll
            for (int m = 0; m < 32; m++) v[m] += __shfl_xor(v[m], step);
        }
        unsigned long long mask = __ballot(valid);
        int lane = threadIdx.x & 63;
        if (lane == 0) {
#pragma unroll
            for (int m = 0; m < 32; m++) atomicAdd(&psum[g0 * 32 + m], v[m]);
            atomicAdd(&pcnt[g0], (int)__popcll(mask));
        }
    } else {
        if (valid) {
#pragma unroll
            for (int m = 0; m < 32; m++) atomicAdd(&psum[g * 32 + m], v[m]);
            atomicAdd(&pcnt[g], 1);
        }
    }
}

// out[g][o] = (sum_m psum[g][m] * Wl[m][o]) / max(cnt,1) + bl[o]
__global__ void k_out(const float* __restrict__ psum, const int* __restrict__ pcnt,
                      const float* __restrict__ Wl, const float* __restrict__ bl,
                      float* __restrict__ out) {
    int t = blockIdx.x * blockDim.x + threadIdx.x;
    if (t >= N_GRAPHS * 5) return;
    int g = t / 5, o = t % 5;
    float c = (float)max(pcnt[g], 1);
    float acc = 0.f;
#pragma unroll
    for (int m = 0; m < 32; m++) acc += psum[g * 32 + m] * Wl[m * 5 + o];
    out[t] = acc / c + bl[o];
}

extern "C" void kernel_launch(void* const* d_in, const int* in_sizes, int n_in,
                              void* d_out, int out_size, void* d_ws, size_t ws_size,
                              hipStream_t stream) {
    const float* x     = (const float*)d_in[0];
    const int*   ei    = (const int*)d_in[1];
    const int*   batch = (const int*)d_in[2];
    const float* W1    = (const float*)d_in[3];
    const float* b1    = (const float*)d_in[4];
    const float* W2    = (const float*)d_in[5];
    const float* b2    = (const float*)d_in[6];
    const float* Wl    = (const float*)d_in[7];
    const float* bl    = (const float*)d_in[8];
    float* out = (float*)d_out;

    const int n = in_sizes[0] / 7;        // 100000
    const int E = in_sizes[1] / 2;        // 3200000
    const int* row = ei;                  // edge_index[0]
    const int* col = ei + E;              // edge_index[1]

    // workspace carve-up (256B aligned)
    char* p = (char*)d_ws;
    auto alloc = [&](size_t bytes) -> char* {
        char* r = p;
        p += (bytes + 255) & ~(size_t)255;
        return r;
    };
    int*   deg   = (int*)  alloc((size_t)n * 4);
    float* dinv  = (float*)alloc((size_t)n * 4);
    int*   off   = (int*)  alloc((size_t)(n + 1) * 4);
    int*   bsum  = (int*)  alloc(128 * 4);
    int*   bexcl = (int*)  alloc(128 * 4);
    int*   srow  = (int*)  alloc((size_t)E * 4);
    float* wnorm = (float*)alloc((size_t)E * 4);
    float* aggx  = (float*)alloc((size_t)n * 7 * 4);
    float* h1p   = (float*)alloc((size_t)n * 32 * 4);
    float* agg2  = (float*)alloc((size_t)n * 32 * 4);
    float* psum  = (float*)alloc((size_t)N_GRAPHS * 32 * 4);
    int*   pcnt  = (int*)  alloc((size_t)N_GRAPHS * 4);
    int*   cursor = deg;   // deg is dead after k_dinv; reuse as scatter cursor

    hipMemsetAsync(deg, 0, (size_t)n * 4, stream);
    hipMemsetAsync(psum, 0, (size_t)N_GRAPHS * 32 * 4, stream);
    hipMemsetAsync(pcnt, 0, (size_t)N_GRAPHS * 4, stream);

    const int BT = 256;
    int nb_n = (n + BT - 1) / BT;
    int nb_e = (E + BT - 1) / BT;
    int nb_scan = (n + 1023) / 1024;              // 98
    int nb_wave = (n * 64 + BT - 1) / BT;         // one wave per node

    k_deg        <<<nb_e, BT, 0, stream>>>(col, deg, E);
    k_dinv       <<<nb_n, BT, 0, stream>>>(deg, dinv, n);
    k_scan_partial<<<nb_scan, BT, 0, stream>>>(deg, off, bsum, n);
    k_scan_blocks<<<1, 128, 0, stream>>>(bsum, bexcl, nb_scan);
    k_scan_add   <<<nb_n, BT, 0, stream>>>(off, bexcl, n, E);
    hipMemsetAsync(cursor, 0, (size_t)n * 4, stream);   // reuse deg as cursor
    k_scatter    <<<nb_e, BT, 0, stream>>>(row, col, off, cursor, dinv, srow, wnorm, E);
    k_agg1       <<<nb_wave, BT, 0, stream>>>(x, dinv, off, srow, wnorm, aggx, n);
    k_mlp1       <<<nb_n, BT, 0, stream>>>(aggx, W1, b1, W2, h1p, n);
    k_agg2       <<<nb_wave, BT, 0, stream>>>(h1p, dinv, off, srow, wnorm, agg2, n);
    k_pool       <<<nb_n, BT, 0, stream>>>(agg2, b2, batch, psum, pcnt, n);
    k_out        <<<1, 320, 0, stream>>>(psum, pcnt, Wl, bl, out);
}